// Round 3
// baseline (202.602 us; speedup 1.0000x reference)
//
#include <hip/hip_runtime.h>
#include <math.h>

#define D_IN 768
#define NLAB 28

// Layout: state index i = (lane<<6) | r, r = per-thread amp index 0..63.
// State bit b<6  -> register-index bit b.
// State bit b>=6 -> lane bit (b-6).
// Wire w <-> state bit (11-w)  (tensor axis 0 = MSB).

template<int B>
__device__ __forceinline__ void rot_gate(float2 (&a)[64], int lane, const float* U) {
    const float u00r=U[0], u00i=U[1], u01r=U[2], u01i=U[3];
    const float u10r=U[4], u10i=U[5], u11r=U[6], u11i=U[7];
    if constexpr (B < 6) {
        constexpr int m = 1 << B;
#pragma unroll
        for (int r = 0; r < 64; ++r) if (!(r & m)) {
            float2 a0 = a[r], a1 = a[r | m], n0, n1;
            n0.x = u00r*a0.x - u00i*a0.y + u01r*a1.x - u01i*a1.y;
            n0.y = u00r*a0.y + u00i*a0.x + u01r*a1.y + u01i*a1.x;
            n1.x = u10r*a0.x - u10i*a0.y + u11r*a1.x - u11i*a1.y;
            n1.y = u10r*a0.y + u10i*a0.x + u11r*a1.y + u11i*a1.x;
            a[r] = n0; a[r | m] = n1;
        }
    } else {
        constexpr int lm = 1 << (B - 6);
        const bool hi = (lane & lm) != 0;
        // new = co*own + cp*partner ; hi=0: u00*own+u01*p ; hi=1: u11*own+u10*p
        const float cor = hi ? u11r : u00r, coi = hi ? u11i : u00i;
        const float cpr = hi ? u10r : u01r, cpi = hi ? u10i : u01i;
#pragma unroll
        for (int r = 0; r < 64; ++r) {
            const float px = __shfl_xor(a[r].x, lm, 64);
            const float py = __shfl_xor(a[r].y, lm, 64);
            const float nx = cor*a[r].x - coi*a[r].y + cpr*px - cpi*py;
            const float ny = cor*a[r].y + coi*a[r].x + cpr*py + cpi*px;
            a[r].x = nx; a[r].y = ny;
        }
    }
}

template<int BC, int BT>
__device__ __forceinline__ void cnot_gate(float2 (&a)[64], int lane) {
    if constexpr (BC < 6 && BT < 6) {            // both reg: predicate-free swap
        constexpr int mc = 1 << BC, mt = 1 << BT;
#pragma unroll
        for (int r = 0; r < 64; ++r) if ((r & mc) && !(r & mt)) {
            float2 t = a[r]; a[r] = a[r | mt]; a[r | mt] = t;
        }
    } else if constexpr (BC >= 6 && BT < 6) {    // ctrl lane, tgt reg: predicated swap
        constexpr int lm = 1 << (BC - 6), mt = 1 << BT;
        const bool c1 = (lane & lm) != 0;
#pragma unroll
        for (int r = 0; r < 64; ++r) if (!(r & mt)) {
            float2 lo = a[r], hi = a[r | mt];
            a[r]      = c1 ? hi : lo;
            a[r | mt] = c1 ? lo : hi;
        }
    } else if constexpr (BC < 6 && BT >= 6) {    // ctrl reg, tgt lane: shfl c=1 half
        constexpr int mc = 1 << BC, lm = 1 << (BT - 6);
#pragma unroll
        for (int r = 0; r < 64; ++r) if (r & mc) {
            a[r].x = __shfl_xor(a[r].x, lm, 64);
            a[r].y = __shfl_xor(a[r].y, lm, 64);
        }
    } else {                                     // both lane: exchange, keep if c=1
        constexpr int lmc = 1 << (BC - 6), lmt = 1 << (BT - 6);
        const bool c1 = (lane & lmc) != 0;
#pragma unroll
        for (int r = 0; r < 64; ++r) {
            const float px = __shfl_xor(a[r].x, lmt, 64);
            const float py = __shfl_xor(a[r].y, lmt, 64);
            if (c1) { a[r].x = px; a[r].y = py; }
        }
    }
}

template<int L, int W>
__device__ __forceinline__ void rots(float2 (&a)[64], int lane, const float (*rotU)[8]) {
    if constexpr (W < 12) {
        rot_gate<11 - W>(a, lane, rotU[L * 12 + W]);
        rots<L, W + 1>(a, lane, rotU);
    }
}
template<int L, int W>
__device__ __forceinline__ void cnots(float2 (&a)[64], int lane) {
    if constexpr (W < 12) {
        cnot_gate<11 - W, 11 - ((W + L + 1) % 12)>(a, lane);
        cnots<L, W + 1>(a, lane);
    }
}

__global__ __launch_bounds__(64, 1) void hybrid_wave(
    const float* __restrict__ x, const float* __restrict__ proj_w,
    const float* __restrict__ proj_b, const float* __restrict__ ln_w,
    const float* __restrict__ ln_b, const float* __restrict__ q_w,
    const float* __restrict__ h1_w, const float* __restrict__ h1_b,
    const float* __restrict__ h2_w, const float* __restrict__ h2_b,
    float* __restrict__ out) {
    __shared__ float rotU[36][8];

    const int b = blockIdx.x;
    const int lane = threadIdx.x;  // 0..63, single wave per block

    // ---- projection: h[j] = tanh(x[b].proj_w[j] + proj_b[j]), all lanes get all 12 ----
    float h[12];
    {
        const float* xr = x + (size_t)b * D_IN;
        float xv[12];
#pragma unroll
        for (int k = 0; k < 12; ++k) xv[k] = xr[lane + k * 64];
#pragma unroll
        for (int j = 0; j < 12; ++j) {
            const float* wr = proj_w + j * D_IN;
            float s = 0.f;
#pragma unroll
            for (int k = 0; k < 12; ++k) s += xv[k] * wr[lane + k * 64];
#pragma unroll
            for (int m = 32; m; m >>= 1) s += __shfl_xor(s, m, 64);
            h[j] = tanhf(s + proj_b[j]);
        }
    }

    // ---- Rot matrices (lanes 0..35); layer-0 fused with embedding RY (lanes 0..11) ----
    if (lane < 36) {
        const float phi = q_w[3 * lane], th = q_w[3 * lane + 1], om = q_w[3 * lane + 2];
        float sth, cth, sa, ca, sb, cb;
        sincosf(0.5f * th, &sth, &cth);
        sincosf(0.5f * (phi + om), &sa, &ca);
        sincosf(0.5f * (phi - om), &sb, &cb);
        float R0r =  cth * ca, R0i = -cth * sa;   // U00
        float R1r = -sth * cb, R1i = -sth * sb;   // U01
        float R2r =  sth * cb, R2i = -sth * sb;   // U10
        float R3r =  cth * ca, R3i =  cth * sa;   // U11
        if (lane < 12) {
            // LayerNorm -> angle -> RY coeffs; fuse M = Rot * RY
            float mu = 0.f;
#pragma unroll
            for (int k = 0; k < 12; ++k) mu += h[k];
            mu *= (1.f / 12.f);
            float var = 0.f;
#pragma unroll
            for (int k = 0; k < 12; ++k) { const float d = h[k] - mu; var += d * d; }
            var *= (1.f / 12.f);
            const float inv = 1.f / sqrtf(var + 1e-5f);
            const float ang = (h[lane] - mu) * inv * ln_w[lane] + ln_b[lane];
            float sy, cy;
            sincosf(0.5f * ang, &sy, &cy);
            // M col0 = R*(cy,sy)^T, M col1 = R*(-sy,cy)^T
            const float M0r = R0r * cy + R1r * sy, M0i = R0i * cy + R1i * sy;
            const float M1r = -R0r * sy + R1r * cy, M1i = -R0i * sy + R1i * cy;
            const float M2r = R2r * cy + R3r * sy, M2i = R2i * cy + R3i * sy;
            const float M3r = -R2r * sy + R3r * cy, M3i = -R2i * sy + R3i * cy;
            R0r = M0r; R0i = M0i; R1r = M1r; R1i = M1i;
            R2r = M2r; R2i = M2i; R3r = M3r; R3i = M3i;
        }
        rotU[lane][0] = R0r; rotU[lane][1] = R0i;
        rotU[lane][2] = R1r; rotU[lane][3] = R1i;
        rotU[lane][4] = R2r; rotU[lane][5] = R2i;
        rotU[lane][6] = R3r; rotU[lane][7] = R3i;
    }
    __syncthreads();

    // ---- state: 64 amps/thread, |0...0> ----
    float2 a[64];
#pragma unroll
    for (int r = 0; r < 64; ++r) a[r] = make_float2(0.f, 0.f);
    if (lane == 0) a[0].x = 1.f;

    // ---- circuit: (embed⊗L0-Rot) + ring1, L1-Rot + ring2, L2-Rot (ring3 absorbed) ----
    rots<0, 0>(a, lane, rotU);
    cnots<0, 0>(a, lane);
    rots<1, 0>(a, lane, rotU);
    cnots<1, 0>(a, lane);
    rots<2, 0>(a, lane, rotU);
    // layer-2 CNOT ring (stride 3) absorbed into measurement sign masks below.

    // ---- measurement: z_w = sum_i (-1)^{<M_b, i>} |psi_i|^2, b=11-w ----
    // GF(2) masks after ring-3 permutation: per-r (low 6 bits) distinct masks:
    // {0,3},{1,4},{2,5},{3},{4},{5}; plus total prob.
    float s03 = 0.f, s14 = 0.f, s25 = 0.f, s3 = 0.f, s4 = 0.f, s5 = 0.f, pt = 0.f;
#pragma unroll
    for (int r = 0; r < 64; ++r) {
        const float p = a[r].x * a[r].x + a[r].y * a[r].y;
        pt += p;
        s03 += ((((r >> 0) ^ (r >> 3)) & 1) ? -p : p);
        s14 += ((((r >> 1) ^ (r >> 4)) & 1) ? -p : p);
        s25 += ((((r >> 2) ^ (r >> 5)) & 1) ? -p : p);
        s3  += ((r & 8)  ? -p : p);
        s4  += ((r & 16) ? -p : p);
        s5  += ((r & 32) ? -p : p);
    }
    // wire w -> (base over r) and lane-bit parity mask (bits of lane):
    const float base[12]  = {s25, s14, s03, pt, pt, pt, s5, s4, s3, s25, s14, s03};
    constexpr int lmask[12] = {4, 2, 1, 36, 18, 9, 36, 18, 9, 36, 18, 9};
    float q[12];
#pragma unroll
    for (int w = 0; w < 12; ++w) {
        float v = (__popc(lane & lmask[w]) & 1) ? -base[w] : base[w];
#pragma unroll
        for (int m = 32; m; m >>= 1) v += __shfl_xor(v, m, 64);
        q[w] = v;
    }

    // ---- MLP: 256 hidden (4/lane), then 28 outputs via butterfly ----
    float z1[4];
#pragma unroll
    for (int j = 0; j < 4; ++j) {
        const int o = lane * 4 + j;
        const float* wr = h1_w + o * 12;
        float s = h1_b[o];
#pragma unroll
        for (int k = 0; k < 12; ++k) s += q[k] * wr[k];
        z1[j] = fmaxf(s, 0.f);
    }
#pragma unroll
    for (int j = 0; j < NLAB; ++j) {
        const float* wr = h2_w + j * 256 + lane * 4;
        float s = z1[0] * wr[0] + z1[1] * wr[1] + z1[2] * wr[2] + z1[3] * wr[3];
#pragma unroll
        for (int m = 32; m; m >>= 1) s += __shfl_xor(s, m, 64);
        if (lane == j) out[(size_t)b * NLAB + j] = s + h2_b[j];
    }
}

extern "C" void kernel_launch(void* const* d_in, const int* in_sizes, int n_in,
                              void* d_out, int out_size, void* d_ws, size_t ws_size,
                              hipStream_t stream) {
    const float* x      = (const float*)d_in[0];
    const float* proj_w = (const float*)d_in[1];
    const float* proj_b = (const float*)d_in[2];
    const float* ln_w   = (const float*)d_in[3];
    const float* ln_b   = (const float*)d_in[4];
    const float* q_w    = (const float*)d_in[5];
    const float* h1_w   = (const float*)d_in[6];
    const float* h1_b   = (const float*)d_in[7];
    const float* h2_w   = (const float*)d_in[8];
    const float* h2_b   = (const float*)d_in[9];
    float* out = (float*)d_out;

    const int B = in_sizes[0] / D_IN;  // 512
    hybrid_wave<<<dim3(B), dim3(64), 0, stream>>>(x, proj_w, proj_b, ln_w, ln_b,
                                                  q_w, h1_w, h1_b, h2_w, h2_b, out);
}

// Round 4
// 42.263 us; speedup vs baseline: 4.7938x; 4.7938x over previous
//
#include <hip/hip_runtime.h>
#include <math.h>

#define D_IN 768
#define NLAB 28

// ================= bit-location maps per epoch =================
// state index i (12 bits). Per epoch e: i = Σ r_k<<rb[k] | Σ lane_j<<lb[j] | Σ wv_m<<wb[m]
struct Map { int rb[4]; int lb[6]; int wb[2]; };
constexpr Map MP[4] = {
    {{8, 9, 10, 11}, {2, 3, 4, 5, 6, 7}, {0, 1}},
    {{0, 1, 2, 3}, {4, 5, 8, 9, 10, 11}, {6, 7}},
    {{4, 5, 6, 7}, {0, 1, 2, 3, 10, 11}, {8, 9}},
    {{8, 9, 10, 11}, {2, 3, 4, 5, 6, 7}, {0, 1}},
};
constexpr int regPos(int e, int b) { for (int k = 0; k < 4; ++k) if (MP[e].rb[k] == b) return k; return -1; }
constexpr int lanePos(int e, int b) { for (int j = 0; j < 6; ++j) if (MP[e].lb[j] == b) return j; return -1; }
constexpr int wavePos(int e, int b) { for (int m = 0; m < 2; ++m) if (MP[e].wb[m] == b) return m; return -1; }

constexpr int stateOf(int e, int wv, int lane, int r) {
    int i = 0;
    for (int k = 0; k < 4; ++k) i |= ((r >> k) & 1) << MP[e].rb[k];
    for (int j = 0; j < 6; ++j) i |= ((lane >> j) & 1) << MP[e].lb[j];
    for (int m = 0; m < 2; ++m) i |= ((wv >> m) & 1) << MP[e].wb[m];
    return i;
}
constexpr int slotOf(int e, int i) {  // writer-linear slot under mapping e
    int r = 0, ln = 0, wv = 0;
    for (int k = 0; k < 4; ++k) r |= ((i >> MP[e].rb[k]) & 1) << k;
    for (int j = 0; j < 6; ++j) ln |= ((i >> MP[e].lb[j]) & 1) << j;
    for (int m = 0; m < 2; ++m) wv |= ((i >> MP[e].wb[m]) & 1) << m;
    return (wv << 10) | (ln << 4) | r;
}
constexpr int swzl(int s) { return s ^ (((s >> 4) ^ (s >> 8)) & 15); }  // GF(2)-linear

// ================= cross-lane exchange: lane-bit j, cheapest primitive =================
template <int J>
__device__ __forceinline__ float lx(float v) {
    if constexpr (J == 0 || J == 1 || J == 3) {
        // xor1: quad_perm[1,0,3,2]=0xB1; xor2: quad_perm[2,3,0,1]=0x4E; xor8: row_ror:8=0x128
        constexpr int ctrl = (J == 0) ? 0xB1 : (J == 1) ? 0x4E : 0x128;
        return __int_as_float(__builtin_amdgcn_update_dpp(
            0, __float_as_int(v), ctrl, 0xF, 0xF, true));
    } else if constexpr (J == 2 || J == 4) {
        // ds_swizzle BitMode: xor<<10 | and 0x1F
        constexpr int off = (J == 2) ? 0x101F : 0x401F;
        return __int_as_float(__builtin_amdgcn_ds_swizzle(__float_as_int(v), off));
    } else {
        return __shfl_xor(v, 32, 64);
    }
}

struct U8 { float4 a, b; };  // u00r,u00i,u01r,u01i | u10r,u10i,u11r,u11i

// ================= gates =================
template <int E, int B>
__device__ __forceinline__ void rot(float2 (&a)[16], int lane, const U8* up) {
    const U8 u = *up;
    const float u00r = u.a.x, u00i = u.a.y, u01r = u.a.z, u01i = u.a.w;
    const float u10r = u.b.x, u10i = u.b.y, u11r = u.b.z, u11i = u.b.w;
    constexpr int k = regPos(E, B);
    if constexpr (k >= 0) {
        constexpr int m = 1 << k;
#pragma unroll
        for (int r = 0; r < 16; ++r)
            if (!(r & m)) {
                const float2 a0 = a[r], a1 = a[r | m];
                float2 n0, n1;
                n0.x = u00r * a0.x - u00i * a0.y + u01r * a1.x - u01i * a1.y;
                n0.y = u00r * a0.y + u00i * a0.x + u01r * a1.y + u01i * a1.x;
                n1.x = u10r * a0.x - u10i * a0.y + u11r * a1.x - u11i * a1.y;
                n1.y = u10r * a0.y + u10i * a0.x + u11r * a1.y + u11i * a1.x;
                a[r] = n0; a[r | m] = n1;
            }
    } else {
        constexpr int j = lanePos(E, B);
        static_assert(j >= 0, "rot on wave bit");
        const bool hi = (lane >> j) & 1;
        const float cor = hi ? u11r : u00r, coi = hi ? u11i : u00i;
        const float cpr = hi ? u10r : u01r, cpi = hi ? u10i : u01i;
#pragma unroll
        for (int r = 0; r < 16; ++r) {
            const float px = lx<j>(a[r].x), py = lx<j>(a[r].y);
            const float nx = cor * a[r].x - coi * a[r].y + cpr * px - cpi * py;
            const float ny = cor * a[r].y + coi * a[r].x + cpr * py + cpi * px;
            a[r].x = nx; a[r].y = ny;
        }
    }
}

template <int E, int C, int T>
__device__ __forceinline__ void cnot(float2 (&a)[16], int lane, int wv) {
    constexpr int kc = regPos(E, C), jc = lanePos(E, C), mc = wavePos(E, C);
    constexpr int kt = regPos(E, T), jt = lanePos(E, T);
    static_assert(wavePos(E, T) < 0, "cnot target on wave bit");
    if constexpr (kt >= 0) {
        constexpr int mt = 1 << kt;
        if constexpr (kc >= 0) {
            constexpr int mcb = 1 << kc;
#pragma unroll
            for (int r = 0; r < 16; ++r)
                if ((r & mcb) && !(r & mt)) { float2 t = a[r]; a[r] = a[r | mt]; a[r | mt] = t; }
        } else if constexpr (jc >= 0) {
            const bool p = (lane >> jc) & 1;
#pragma unroll
            for (int r = 0; r < 16; ++r)
                if (!(r & mt)) {
                    const float2 lo = a[r], hi = a[r | mt];
                    a[r].x = p ? hi.x : lo.x;  a[r].y = p ? hi.y : lo.y;
                    a[r | mt].x = p ? lo.x : hi.x;  a[r | mt].y = p ? lo.y : hi.y;
                }
        } else {
            if ((wv >> mc) & 1) {
#pragma unroll
                for (int r = 0; r < 16; ++r)
                    if (!(r & mt)) { float2 t = a[r]; a[r] = a[r | mt]; a[r | mt] = t; }
            }
        }
    } else {  // target on lane bit jt
        if constexpr (kc >= 0) {
            constexpr int mcb = 1 << kc;
#pragma unroll
            for (int r = 0; r < 16; ++r)
                if (r & mcb) { a[r].x = lx<jt>(a[r].x); a[r].y = lx<jt>(a[r].y); }
        } else if constexpr (jc >= 0) {
            const bool p = (lane >> jc) & 1;
#pragma unroll
            for (int r = 0; r < 16; ++r) {
                const float px = lx<jt>(a[r].x), py = lx<jt>(a[r].y);
                a[r].x = p ? px : a[r].x;  a[r].y = p ? py : a[r].y;
            }
        } else {
            if ((wv >> mc) & 1) {
#pragma unroll
                for (int r = 0; r < 16; ++r) { a[r].x = lx<jt>(a[r].x); a[r].y = lx<jt>(a[r].y); }
            }
        }
    }
}

// remap: write whole state with mapping PE (linear slots, swizzled), read with mapping CE
template <int PE, int CE>
__device__ __forceinline__ void remap(float2 (&a)[16], int lane, int wv, float2* st) {
    const int wbase = swzl((wv << 10) | (lane << 4));
#pragma unroll
    for (int r = 0; r < 16; ++r) st[wbase ^ r] = a[r];
    __syncthreads();
    const int rbase = swzl(slotOf(PE, stateOf(CE, wv, lane, 0)));
#pragma unroll
    for (int r = 0; r < 16; ++r) {
        const int d = swzl(slotOf(PE, stateOf(CE, 0, 0, r)));  // compile-time folds
        a[r] = st[rbase ^ d];
    }
    __syncthreads();
}

// ================= kernel =================
__global__ __launch_bounds__(256, 2) void hybrid_r4(
    const float* __restrict__ x, const float* __restrict__ proj_w,
    const float* __restrict__ proj_b, const float* __restrict__ ln_w,
    const float* __restrict__ ln_b, const float* __restrict__ q_w,
    const float* __restrict__ h1_w, const float* __restrict__ h1_b,
    const float* __restrict__ h2_w, const float* __restrict__ h2_b,
    float* __restrict__ out) {
    __shared__ float2 st[4096];   // 32 KB remap buffer
    __shared__ U8 rotU[36];
    __shared__ float hbuf[12];
    __shared__ float red[48];
    __shared__ float z1[256];
    __shared__ float qz[12];

    const int b = blockIdx.x;
    const int tid = threadIdx.x;
    const int lane = tid & 63;
    const int wv = tid >> 6;

    // ---- 1. projection h[j] = tanh(x[b].proj_w[j] + proj_b[j]) ----
    {
        const float* xr = x + (size_t)b * D_IN;
        float xv[12];
#pragma unroll
        for (int k = 0; k < 12; ++k) xv[k] = xr[lane + k * 64];
#pragma unroll
        for (int jj = 0; jj < 3; ++jj) {
            const int j = wv * 3 + jj;
            const float* wr = proj_w + j * D_IN;
            float s = 0.f;
#pragma unroll
            for (int k = 0; k < 12; ++k) s += xv[k] * wr[lane + k * 64];
#pragma unroll
            for (int m = 32; m; m >>= 1) s += __shfl_xor(s, m, 64);
            if (lane == 0) hbuf[j] = tanhf(s + proj_b[j]);
        }
    }
    __syncthreads();

    // ---- 2. Rot matrices; layer-0 fused with LayerNorm+RY ----
    if (tid < 36) {
        const float phi = q_w[3 * tid], th = q_w[3 * tid + 1], om = q_w[3 * tid + 2];
        float sth, cth, sa, ca, sb, cb;
        sincosf(0.5f * th, &sth, &cth);
        sincosf(0.5f * (phi + om), &sa, &ca);
        sincosf(0.5f * (phi - om), &sb, &cb);
        float R0r = cth * ca, R0i = -cth * sa;    // U00
        float R1r = -sth * cb, R1i = -sth * sb;   // U01
        float R2r = sth * cb, R2i = -sth * sb;    // U10
        float R3r = cth * ca, R3i = cth * sa;     // U11
        if (tid < 12) {
            float mu = 0.f;
#pragma unroll
            for (int k = 0; k < 12; ++k) mu += hbuf[k];
            mu *= (1.f / 12.f);
            float var = 0.f;
#pragma unroll
            for (int k = 0; k < 12; ++k) { const float d = hbuf[k] - mu; var += d * d; }
            var *= (1.f / 12.f);
            const float inv = 1.f / sqrtf(var + 1e-5f);
            const float ang = (hbuf[tid] - mu) * inv * ln_w[tid] + ln_b[tid];
            float sy, cy;
            sincosf(0.5f * ang, &sy, &cy);
            const float M0r = R0r * cy + R1r * sy, M0i = R0i * cy + R1i * sy;
            const float M1r = -R0r * sy + R1r * cy, M1i = -R0i * sy + R1i * cy;
            const float M2r = R2r * cy + R3r * sy, M2i = R2i * cy + R3i * sy;
            const float M3r = -R2r * sy + R3r * cy, M3i = -R2i * sy + R3i * cy;
            R0r = M0r; R0i = M0i; R1r = M1r; R1i = M1i;
            R2r = M2r; R2i = M2i; R3r = M3r; R3i = M3i;
        }
        rotU[tid].a = make_float4(R0r, R0i, R1r, R1i);
        rotU[tid].b = make_float4(R2r, R2i, R3r, R3i);
    }
    __syncthreads();

    // ---- 3. state init |0..0> (E0 mapping: i=0 -> wv=0,lane=0,r=0) ----
    float2 a[16];
#pragma unroll
    for (int r = 0; r < 16; ++r) a[r] = make_float2(0.f, 0.f);
    if (tid == 0) a[0].x = 1.f;

    // ---- 4. circuit ----
    // E0: WB={0,1}. L0 Rots wires 0..9 (bits 11..2); ring1 (11,10)..(3,2)
    rot<0, 11>(a, lane, &rotU[0]);  rot<0, 10>(a, lane, &rotU[1]);
    rot<0, 9>(a, lane, &rotU[2]);   rot<0, 8>(a, lane, &rotU[3]);
    rot<0, 7>(a, lane, &rotU[4]);   rot<0, 6>(a, lane, &rotU[5]);
    rot<0, 5>(a, lane, &rotU[6]);   rot<0, 4>(a, lane, &rotU[7]);
    rot<0, 3>(a, lane, &rotU[8]);   rot<0, 2>(a, lane, &rotU[9]);
    cnot<0, 11, 10>(a, lane, wv); cnot<0, 10, 9>(a, lane, wv);
    cnot<0, 9, 8>(a, lane, wv);   cnot<0, 8, 7>(a, lane, wv);
    cnot<0, 7, 6>(a, lane, wv);   cnot<0, 6, 5>(a, lane, wv);
    cnot<0, 5, 4>(a, lane, wv);   cnot<0, 4, 3>(a, lane, wv);
    cnot<0, 3, 2>(a, lane, wv);
    remap<0, 1>(a, lane, wv, st);
    // E1: WB={6,7}. L0 Rots wires 10,11 (bits 1,0); ring1 leftovers; L1 Rots (skip bits 7,6); ring2 (11,9),(10,8)
    rot<1, 1>(a, lane, &rotU[10]);  rot<1, 0>(a, lane, &rotU[11]);
    cnot<1, 2, 1>(a, lane, wv); cnot<1, 1, 0>(a, lane, wv); cnot<1, 0, 11>(a, lane, wv);
    rot<1, 11>(a, lane, &rotU[12]); rot<1, 10>(a, lane, &rotU[13]);
    rot<1, 9>(a, lane, &rotU[14]);  rot<1, 8>(a, lane, &rotU[15]);
    rot<1, 5>(a, lane, &rotU[18]);  rot<1, 4>(a, lane, &rotU[19]);
    rot<1, 3>(a, lane, &rotU[20]);  rot<1, 2>(a, lane, &rotU[21]);
    rot<1, 1>(a, lane, &rotU[22]);  rot<1, 0>(a, lane, &rotU[23]);
    cnot<1, 11, 9>(a, lane, wv); cnot<1, 10, 8>(a, lane, wv);
    remap<1, 2>(a, lane, wv, st);
    // E2: WB={8,9}. L1 Rots bits 7,6; rest of ring2; L2 Rots (skip bits 9,8)
    rot<2, 7>(a, lane, &rotU[16]);  rot<2, 6>(a, lane, &rotU[17]);
    cnot<2, 9, 7>(a, lane, wv);  cnot<2, 8, 6>(a, lane, wv);
    cnot<2, 7, 5>(a, lane, wv);  cnot<2, 6, 4>(a, lane, wv);
    cnot<2, 5, 3>(a, lane, wv);  cnot<2, 4, 2>(a, lane, wv);
    cnot<2, 3, 1>(a, lane, wv);  cnot<2, 2, 0>(a, lane, wv);
    cnot<2, 1, 11>(a, lane, wv); cnot<2, 0, 10>(a, lane, wv);
    rot<2, 11>(a, lane, &rotU[24]); rot<2, 10>(a, lane, &rotU[25]);
    rot<2, 7>(a, lane, &rotU[28]);  rot<2, 6>(a, lane, &rotU[29]);
    rot<2, 5>(a, lane, &rotU[30]);  rot<2, 4>(a, lane, &rotU[31]);
    rot<2, 3>(a, lane, &rotU[32]);  rot<2, 2>(a, lane, &rotU[33]);
    rot<2, 1>(a, lane, &rotU[34]);  rot<2, 0>(a, lane, &rotU[35]);
    remap<2, 3>(a, lane, wv, st);
    // E3: WB={0,1}. L2 Rots bits 9,8 (wires 2,3). Ring3 absorbed into measurement.
    rot<3, 9>(a, lane, &rotU[26]);  rot<3, 8>(a, lane, &rotU[27]);

    // ---- 5. measurement: ring3-absorbed GF(2) sign masks, E3 mapping ----
    // r-sum selectors and lane/wave parity masks per wire:
    // RM in {0:tot,1,2,4,9}; LM over lane bits; WM over wave bits.
    {
        float s0 = 0.f, s1 = 0.f, s2 = 0.f, s4 = 0.f, s9 = 0.f;
#pragma unroll
        for (int r = 0; r < 16; ++r) {
            const float p = a[r].x * a[r].x + a[r].y * a[r].y;
            s0 += p;
            s1 += (__builtin_popcount(r & 1) & 1) ? -p : p;
            s2 += (__builtin_popcount(r & 2) & 1) ? -p : p;
            s4 += (__builtin_popcount(r & 4) & 1) ? -p : p;
            s9 += (__builtin_popcount(r & 9) & 1) ? -p : p;
        }
        const float base[12] = {s1, s0, s0, s9, s4, s2, s9, s4, s2, s9, s4, s2};
        constexpr int LM[12] = {9, 36, 18, 0, 32, 16, 8, 36, 18, 9, 36, 18};
        constexpr int WM[12] = {0, 2, 1, 0, 0, 0, 0, 0, 0, 0, 2, 1};
#pragma unroll
        for (int w = 0; w < 12; ++w) {
            const int sgn = (__popc(lane & LM[w]) + __popc(wv & WM[w])) & 1;
            float v = sgn ? -base[w] : base[w];
#pragma unroll
            for (int m = 32; m; m >>= 1) v += __shfl_xor(v, m, 64);
            if (lane == 0) red[w * 4 + wv] = v;
        }
    }
    __syncthreads();
    if (tid < 12)
        qz[tid] = red[tid * 4 + 0] + red[tid * 4 + 1] + red[tid * 4 + 2] + red[tid * 4 + 3];
    __syncthreads();

    // ---- 6. MLP hidden: relu(q @ h1_w.T + h1_b) ----
    {
        float s = h1_b[tid];
#pragma unroll
        for (int k = 0; k < 12; ++k) s += qz[k] * h1_w[tid * 12 + k];
        z1[tid] = fmaxf(s, 0.f);
    }
    __syncthreads();

    // ---- 7. out = z1 @ h2_w.T + h2_b ----
#pragma unroll
    for (int jj = 0; jj < 7; ++jj) {
        const int j = wv * 7 + jj;
        const float* wr = h2_w + j * 256;
        float s = 0.f;
#pragma unroll
        for (int k = 0; k < 4; ++k) s += z1[lane + k * 64] * wr[lane + k * 64];
#pragma unroll
        for (int m = 32; m; m >>= 1) s += __shfl_xor(s, m, 64);
        if (lane == 0) out[(size_t)b * NLAB + j] = s + h2_b[j];
    }
}

extern "C" void kernel_launch(void* const* d_in, const int* in_sizes, int n_in,
                              void* d_out, int out_size, void* d_ws, size_t ws_size,
                              hipStream_t stream) {
    const float* x      = (const float*)d_in[0];
    const float* proj_w = (const float*)d_in[1];
    const float* proj_b = (const float*)d_in[2];
    const float* ln_w   = (const float*)d_in[3];
    const float* ln_b   = (const float*)d_in[4];
    const float* q_w    = (const float*)d_in[5];
    const float* h1_w   = (const float*)d_in[6];
    const float* h1_b   = (const float*)d_in[7];
    const float* h2_w   = (const float*)d_in[8];
    const float* h2_b   = (const float*)d_in[9];
    float* out = (float*)d_out;

    const int B = in_sizes[0] / D_IN;  // 512
    hybrid_r4<<<dim3(B), dim3(256), 0, stream>>>(x, proj_w, proj_b, ln_w, ln_b,
                                                 q_w, h1_w, h1_b, h2_w, h2_b, out);
}

// Round 5
// 38.630 us; speedup vs baseline: 5.2446x; 1.0940x over previous
//
#include <hip/hip_runtime.h>
#include <math.h>

#define D_IN 768
#define NLAB 28

// ================= bit-location maps per epoch =================
// state index i (12 bits): i = Σ r_k<<rb[k] | Σ lane_j<<lb[j] | Σ wv_m<<wb[m]
struct Map { int rb[3]; int lb[6]; int wb[3]; };
constexpr Map MP[4] = {
    {{9, 10, 11}, {3, 4, 5, 6, 7, 8}, {0, 1, 2}},
    {{0, 1, 2}, {3, 7, 8, 9, 10, 11}, {4, 5, 6}},
    {{0, 1, 2}, {3, 4, 5, 6, 7, 8}, {9, 10, 11}},
    {{0, 1, 2}, {3, 7, 8, 9, 10, 11}, {4, 5, 6}},
};
constexpr int regPos(int e, int b) { for (int k = 0; k < 3; ++k) if (MP[e].rb[k] == b) return k; return -1; }
constexpr int lanePos(int e, int b) { for (int j = 0; j < 6; ++j) if (MP[e].lb[j] == b) return j; return -1; }
constexpr int wavePos(int e, int b) { for (int m = 0; m < 3; ++m) if (MP[e].wb[m] == b) return m; return -1; }

constexpr int stateOf(int e, int wv, int lane, int r) {
    int i = 0;
    for (int k = 0; k < 3; ++k) i |= ((r >> k) & 1) << MP[e].rb[k];
    for (int j = 0; j < 6; ++j) i |= ((lane >> j) & 1) << MP[e].lb[j];
    for (int m = 0; m < 3; ++m) i |= ((wv >> m) & 1) << MP[e].wb[m];
    return i;
}
constexpr int slotOf(int e, int i) {
    int r = 0, ln = 0, wv = 0;
    for (int k = 0; k < 3; ++k) r |= ((i >> MP[e].rb[k]) & 1) << k;
    for (int j = 0; j < 6; ++j) ln |= ((i >> MP[e].lb[j]) & 1) << j;
    for (int m = 0; m < 3; ++m) wv |= ((i >> MP[e].wb[m]) & 1) << m;
    return (wv << 9) | (ln << 3) | r;
}
constexpr int swzl(int s) { return s ^ (((s >> 3) ^ (s >> 6) ^ (s >> 9)) & 7); }  // GF(2)-linear

// ================= cross-lane exchange at distance 2^J =================
template <int J>
__device__ __forceinline__ float lx(float v) {
    if constexpr (J == 0 || J == 1 || J == 3) {
        // xor1: quad_perm[1,0,3,2]=0xB1; xor2: quad_perm[2,3,0,1]=0x4E; xor8: row_ror:8=0x128
        constexpr int ctrl = (J == 0) ? 0xB1 : (J == 1) ? 0x4E : 0x128;
        return __int_as_float(__builtin_amdgcn_update_dpp(
            0, __float_as_int(v), ctrl, 0xF, 0xF, true));
    } else if constexpr (J == 2 || J == 4) {
        constexpr int off = (J == 2) ? 0x101F : 0x401F;  // ds_swizzle xor4 / xor16
        return __int_as_float(__builtin_amdgcn_ds_swizzle(__float_as_int(v), off));
    } else {
        return __shfl_xor(v, 32, 64);
    }
}
__device__ __forceinline__ float waveRed(float v) {
    v += lx<0>(v); v += lx<1>(v); v += lx<2>(v);
    v += lx<3>(v); v += lx<4>(v); v += lx<5>(v);
    return v;
}

struct U8 { float4 a, b; };  // u00r,u00i,u01r,u01i | u10r,u10i,u11r,u11i

// ================= gates =================
template <int E, int B>
__device__ __forceinline__ void rot(float2 (&a)[8], int lane, const U8* up) {
    const U8 u = *up;
    const float u00r = u.a.x, u00i = u.a.y, u01r = u.a.z, u01i = u.a.w;
    const float u10r = u.b.x, u10i = u.b.y, u11r = u.b.z, u11i = u.b.w;
    constexpr int k = regPos(E, B);
    if constexpr (k >= 0) {
        constexpr int m = 1 << k;
#pragma unroll
        for (int r = 0; r < 8; ++r)
            if (!(r & m)) {
                const float2 a0 = a[r], a1 = a[r | m];
                float2 n0, n1;
                n0.x = u00r * a0.x - u00i * a0.y + u01r * a1.x - u01i * a1.y;
                n0.y = u00r * a0.y + u00i * a0.x + u01r * a1.y + u01i * a1.x;
                n1.x = u10r * a0.x - u10i * a0.y + u11r * a1.x - u11i * a1.y;
                n1.y = u10r * a0.y + u10i * a0.x + u11r * a1.y + u11i * a1.x;
                a[r] = n0; a[r | m] = n1;
            }
    } else {
        constexpr int j = lanePos(E, B);
        static_assert(j >= 0, "rot on wave bit");
        const bool hi = (lane >> j) & 1;
        const float cor = hi ? u11r : u00r, coi = hi ? u11i : u00i;
        const float cpr = hi ? u10r : u01r, cpi = hi ? u10i : u01i;
#pragma unroll
        for (int r = 0; r < 8; ++r) {
            const float px = lx<j>(a[r].x), py = lx<j>(a[r].y);
            const float nx = cor * a[r].x - coi * a[r].y + cpr * px - cpi * py;
            const float ny = cor * a[r].y + coi * a[r].x + cpr * py + cpi * px;
            a[r].x = nx; a[r].y = ny;
        }
    }
}

template <int E, int C, int T>
__device__ __forceinline__ void cnot(float2 (&a)[8], int lane, int wv) {
    constexpr int kc = regPos(E, C), jc = lanePos(E, C), mc = wavePos(E, C);
    constexpr int kt = regPos(E, T), jt = lanePos(E, T);
    static_assert(wavePos(E, T) < 0, "cnot target on wave bit");
    if constexpr (kt >= 0) {
        constexpr int mt = 1 << kt;
        if constexpr (kc >= 0) {
            constexpr int mcb = 1 << kc;
#pragma unroll
            for (int r = 0; r < 8; ++r)
                if ((r & mcb) && !(r & mt)) { float2 t = a[r]; a[r] = a[r | mt]; a[r | mt] = t; }
        } else if constexpr (jc >= 0) {
            const bool p = (lane >> jc) & 1;
#pragma unroll
            for (int r = 0; r < 8; ++r)
                if (!(r & mt)) {
                    const float2 lo = a[r], hi = a[r | mt];
                    a[r].x = p ? hi.x : lo.x;  a[r].y = p ? hi.y : lo.y;
                    a[r | mt].x = p ? lo.x : hi.x;  a[r | mt].y = p ? lo.y : hi.y;
                }
        } else {
            if ((wv >> mc) & 1) {
#pragma unroll
                for (int r = 0; r < 8; ++r)
                    if (!(r & mt)) { float2 t = a[r]; a[r] = a[r | mt]; a[r | mt] = t; }
            }
        }
    } else {  // target on lane bit jt
        if constexpr (kc >= 0) {
            constexpr int mcb = 1 << kc;
#pragma unroll
            for (int r = 0; r < 8; ++r)
                if (r & mcb) { a[r].x = lx<jt>(a[r].x); a[r].y = lx<jt>(a[r].y); }
        } else if constexpr (jc >= 0) {
            const bool p = (lane >> jc) & 1;
#pragma unroll
            for (int r = 0; r < 8; ++r) {
                const float px = lx<jt>(a[r].x), py = lx<jt>(a[r].y);
                a[r].x = p ? px : a[r].x;  a[r].y = p ? py : a[r].y;
            }
        } else {
            if ((wv >> mc) & 1) {
#pragma unroll
                for (int r = 0; r < 8; ++r) { a[r].x = lx<jt>(a[r].x); a[r].y = lx<jt>(a[r].y); }
            }
        }
    }
}

// remap: write state with mapping PE (linear slots, swizzled), read with mapping CE
template <int PE, int CE>
__device__ __forceinline__ void remap(float2 (&a)[8], int lane, int wv, float2* st) {
    const int wbase = swzl((wv << 9) | (lane << 3));
#pragma unroll
    for (int r = 0; r < 8; ++r) st[wbase ^ r] = a[r];
    __syncthreads();
    const int rbase = swzl(slotOf(PE, stateOf(CE, wv, lane, 0)));
#pragma unroll
    for (int r = 0; r < 8; ++r) {
        const int d = swzl(slotOf(PE, stateOf(CE, 0, 0, r)));  // compile-time folds
        a[r] = st[rbase ^ d];
    }
    __syncthreads();
}

// ============ measurement masks: ring3 (CNOT(w,w+3)) absorbed, GF(2)-derived ============
// Post-permutation Z mask over ORIGINAL state bits, wire w measured at bit 11-w:
constexpr int MASKW[12] = {0x124, 0x092, 0x049, 0x900, 0x480, 0x240,
                           0x920, 0x490, 0x248, 0x924, 0x492, 0x249};
constexpr int rmOf(int w) { int v = 0; for (int k = 0; k < 3; ++k) v |= ((MASKW[w] >> MP[3].rb[k]) & 1) << k; return v; }
constexpr int lmOf(int w) { int v = 0; for (int j = 0; j < 6; ++j) v |= ((MASKW[w] >> MP[3].lb[j]) & 1) << j; return v; }
constexpr int wmOf(int w) { int v = 0; for (int m = 0; m < 3; ++m) v |= ((MASKW[w] >> MP[3].wb[m]) & 1) << m; return v; }
constexpr int RMa[12] = {rmOf(0),rmOf(1),rmOf(2),rmOf(3),rmOf(4),rmOf(5),rmOf(6),rmOf(7),rmOf(8),rmOf(9),rmOf(10),rmOf(11)};
constexpr int LMa[12] = {lmOf(0),lmOf(1),lmOf(2),lmOf(3),lmOf(4),lmOf(5),lmOf(6),lmOf(7),lmOf(8),lmOf(9),lmOf(10),lmOf(11)};
constexpr int WMa[12] = {wmOf(0),wmOf(1),wmOf(2),wmOf(3),wmOf(4),wmOf(5),wmOf(6),wmOf(7),wmOf(8),wmOf(9),wmOf(10),wmOf(11)};
constexpr bool rmOK() { for (int w = 0; w < 12; ++w) if (RMa[w] != 0 && RMa[w] != 1 && RMa[w] != 2 && RMa[w] != 4) return false; return true; }
static_assert(rmOK(), "RM outside {0,1,2,4}");

// ================= kernel =================
__global__ __launch_bounds__(512, 4) void hybrid_r5(
    const float* __restrict__ x, const float* __restrict__ proj_w,
    const float* __restrict__ proj_b, const float* __restrict__ ln_w,
    const float* __restrict__ ln_b, const float* __restrict__ q_w,
    const float* __restrict__ h1_w, const float* __restrict__ h1_b,
    const float* __restrict__ h2_w, const float* __restrict__ h2_b,
    float* __restrict__ out) {
    __shared__ float2 st[4096];   // 32 KB remap buffer
    __shared__ U8 rotU[36];
    __shared__ float hbuf[12];
    __shared__ float red[12 * 8];
    __shared__ float z1[256];
    __shared__ float qz[12];

    const int b = blockIdx.x;
    const int tid = threadIdx.x;   // 0..511
    const int lane = tid & 63;
    const int wv = tid >> 6;       // 0..7

    // ---- 1. projection h[j] = tanh(x[b].proj_w[j] + proj_b[j]) ----
    {
        const float* xr = x + (size_t)b * D_IN;
        float xv[12];
#pragma unroll
        for (int k = 0; k < 12; ++k) xv[k] = xr[lane + k * 64];
#pragma unroll
        for (int jj = 0; jj < 2; ++jj) {
            const int j = wv + 8 * jj;
            if (j < 12) {
                const float* wr = proj_w + j * D_IN;
                float s = 0.f;
#pragma unroll
                for (int k = 0; k < 12; ++k) s += xv[k] * wr[lane + k * 64];
                s = waveRed(s);
                if (lane == 0) hbuf[j] = tanhf(s + proj_b[j]);
            }
        }
    }
    __syncthreads();

    // ---- 2. Rot matrices; layer-0 fused with LayerNorm+RY ----
    if (tid < 36) {
        const float phi = q_w[3 * tid], th = q_w[3 * tid + 1], om = q_w[3 * tid + 2];
        float sth, cth, sa, ca, sb, cb;
        sincosf(0.5f * th, &sth, &cth);
        sincosf(0.5f * (phi + om), &sa, &ca);
        sincosf(0.5f * (phi - om), &sb, &cb);
        float R0r = cth * ca, R0i = -cth * sa;    // U00
        float R1r = -sth * cb, R1i = -sth * sb;   // U01
        float R2r = sth * cb, R2i = -sth * sb;    // U10
        float R3r = cth * ca, R3i = cth * sa;     // U11
        if (tid < 12) {
            float mu = 0.f;
#pragma unroll
            for (int k = 0; k < 12; ++k) mu += hbuf[k];
            mu *= (1.f / 12.f);
            float var = 0.f;
#pragma unroll
            for (int k = 0; k < 12; ++k) { const float d = hbuf[k] - mu; var += d * d; }
            var *= (1.f / 12.f);
            const float inv = 1.f / sqrtf(var + 1e-5f);
            const float ang = (hbuf[tid] - mu) * inv * ln_w[tid] + ln_b[tid];
            float sy, cy;
            sincosf(0.5f * ang, &sy, &cy);
            const float M0r = R0r * cy + R1r * sy, M0i = R0i * cy + R1i * sy;
            const float M1r = -R0r * sy + R1r * cy, M1i = -R0i * sy + R1i * cy;
            const float M2r = R2r * cy + R3r * sy, M2i = R2i * cy + R3i * sy;
            const float M3r = -R2r * sy + R3r * cy, M3i = -R2i * sy + R3i * cy;
            R0r = M0r; R0i = M0i; R1r = M1r; R1i = M1i;
            R2r = M2r; R2i = M2i; R3r = M3r; R3i = M3i;
        }
        rotU[tid].a = make_float4(R0r, R0i, R1r, R1i);
        rotU[tid].b = make_float4(R2r, R2i, R3r, R3i);
    }
    __syncthreads();

    // ---- 3. state |0..0>: E0 maps i=0 -> wv0,lane0,r0 ----
    float2 a[8];
#pragma unroll
    for (int r = 0; r < 8; ++r) a[r] = make_float2(0.f, 0.f);
    if (tid == 0) a[0].x = 1.f;

    // ---- 4. circuit ----
    // E0: reg={9,10,11} lane={3..8} wave={0,1,2}
    rot<0, 11>(a, lane, &rotU[0]); rot<0, 10>(a, lane, &rotU[1]); rot<0, 9>(a, lane, &rotU[2]);
    rot<0, 8>(a, lane, &rotU[3]);  rot<0, 7>(a, lane, &rotU[4]);  rot<0, 6>(a, lane, &rotU[5]);
    rot<0, 5>(a, lane, &rotU[6]);  rot<0, 4>(a, lane, &rotU[7]);  rot<0, 3>(a, lane, &rotU[8]);
    cnot<0, 11, 10>(a, lane, wv); cnot<0, 10, 9>(a, lane, wv); cnot<0, 9, 8>(a, lane, wv);
    cnot<0, 8, 7>(a, lane, wv);   cnot<0, 7, 6>(a, lane, wv);  cnot<0, 6, 5>(a, lane, wv);
    cnot<0, 5, 4>(a, lane, wv);   cnot<0, 4, 3>(a, lane, wv);
    remap<0, 1>(a, lane, wv, st);
    // E1: reg={0,1,2} lane={3,7,8,9,10,11} wave={4,5,6}
    rot<1, 2>(a, lane, &rotU[9]); rot<1, 1>(a, lane, &rotU[10]); rot<1, 0>(a, lane, &rotU[11]);
    cnot<1, 3, 2>(a, lane, wv); cnot<1, 2, 1>(a, lane, wv);
    cnot<1, 1, 0>(a, lane, wv); cnot<1, 0, 11>(a, lane, wv);
    rot<1, 11>(a, lane, &rotU[12]); rot<1, 10>(a, lane, &rotU[13]); rot<1, 9>(a, lane, &rotU[14]);
    rot<1, 8>(a, lane, &rotU[15]);  rot<1, 7>(a, lane, &rotU[16]);  rot<1, 3>(a, lane, &rotU[20]);
    rot<1, 2>(a, lane, &rotU[21]);  rot<1, 1>(a, lane, &rotU[22]);  rot<1, 0>(a, lane, &rotU[23]);
    cnot<1, 11, 9>(a, lane, wv); cnot<1, 10, 8>(a, lane, wv); cnot<1, 9, 7>(a, lane, wv);
    remap<1, 2>(a, lane, wv, st);
    // E2: reg={0,1,2} lane={3..8} wave={9,10,11}
    rot<2, 6>(a, lane, &rotU[17]); rot<2, 5>(a, lane, &rotU[18]); rot<2, 4>(a, lane, &rotU[19]);
    cnot<2, 8, 6>(a, lane, wv); cnot<2, 7, 5>(a, lane, wv); cnot<2, 6, 4>(a, lane, wv);
    cnot<2, 5, 3>(a, lane, wv); cnot<2, 4, 2>(a, lane, wv); cnot<2, 3, 1>(a, lane, wv);
    cnot<2, 2, 0>(a, lane, wv);
    rot<2, 8>(a, lane, &rotU[27]); rot<2, 7>(a, lane, &rotU[28]); rot<2, 6>(a, lane, &rotU[29]);
    rot<2, 5>(a, lane, &rotU[30]); rot<2, 4>(a, lane, &rotU[31]); rot<2, 3>(a, lane, &rotU[32]);
    rot<2, 2>(a, lane, &rotU[33]);
    remap<2, 3>(a, lane, wv, st);
    // E3: reg={0,1,2} lane={3,7,8,9,10,11} wave={4,5,6}
    cnot<3, 1, 11>(a, lane, wv); cnot<3, 0, 10>(a, lane, wv);
    rot<3, 11>(a, lane, &rotU[24]); rot<3, 10>(a, lane, &rotU[25]); rot<3, 9>(a, lane, &rotU[26]);
    rot<3, 1>(a, lane, &rotU[34]);  rot<3, 0>(a, lane, &rotU[35]);
    // ring3 absorbed into measurement masks.

    // ---- 5. measurement ----
    {
        float pr[8];
#pragma unroll
        for (int r = 0; r < 8; ++r) pr[r] = a[r].x * a[r].x + a[r].y * a[r].y;
        float s0 = 0.f, s1 = 0.f, s2 = 0.f, s4 = 0.f;
#pragma unroll
        for (int r = 0; r < 8; ++r) {
            const float p = pr[r];
            s0 += p;
            s1 += (r & 1) ? -p : p;
            s2 += (r & 2) ? -p : p;
            s4 += (r & 4) ? -p : p;
        }
#pragma unroll
        for (int w = 0; w < 12; ++w) {
            const float base = (RMa[w] == 0) ? s0 : (RMa[w] == 1) ? s1 : (RMa[w] == 2) ? s2 : s4;
            const int sgn = (__popc(lane & LMa[w]) + __popc(wv & WMa[w])) & 1;
            float v = sgn ? -base : base;
            v = waveRed(v);
            if (lane == 0) red[w * 8 + wv] = v;
        }
    }
    __syncthreads();
    if (tid < 12) {
        float q = 0.f;
#pragma unroll
        for (int m = 0; m < 8; ++m) q += red[tid * 8 + m];
        qz[tid] = q;
    }
    __syncthreads();

    // ---- 6. MLP hidden: relu(q @ h1_w.T + h1_b) ----
    if (tid < 256) {
        float s = h1_b[tid];
#pragma unroll
        for (int k = 0; k < 12; ++k) s += qz[k] * h1_w[tid * 12 + k];
        z1[tid] = fmaxf(s, 0.f);
    }
    __syncthreads();

    // ---- 7. out = z1 @ h2_w.T + h2_b : waves 0..6, 4 outputs each ----
    if (wv < 7) {
#pragma unroll
        for (int jj = 0; jj < 4; ++jj) {
            const int j = wv * 4 + jj;
            const float* wr = h2_w + j * 256;
            float s = 0.f;
#pragma unroll
            for (int k = 0; k < 4; ++k) s += z1[lane + k * 64] * wr[lane + k * 64];
            s = waveRed(s);
            if (lane == 0) out[(size_t)b * NLAB + j] = s + h2_b[j];
        }
    }
}

extern "C" void kernel_launch(void* const* d_in, const int* in_sizes, int n_in,
                              void* d_out, int out_size, void* d_ws, size_t ws_size,
                              hipStream_t stream) {
    const float* x      = (const float*)d_in[0];
    const float* proj_w = (const float*)d_in[1];
    const float* proj_b = (const float*)d_in[2];
    const float* ln_w   = (const float*)d_in[3];
    const float* ln_b   = (const float*)d_in[4];
    const float* q_w    = (const float*)d_in[5];
    const float* h1_w   = (const float*)d_in[6];
    const float* h1_b   = (const float*)d_in[7];
    const float* h2_w   = (const float*)d_in[8];
    const float* h2_b   = (const float*)d_in[9];
    float* out = (float*)d_out;

    const int B = in_sizes[0] / D_IN;  // 512
    hybrid_r5<<<dim3(B), dim3(512), 0, stream>>>(x, proj_w, proj_b, ln_w, ln_b,
                                                 q_w, h1_w, h1_b, h2_w, h2_b, out);
}

// Round 6
// 32.934 us; speedup vs baseline: 6.1517x; 1.1730x over previous
//
#include <hip/hip_runtime.h>
#include <math.h>

#define D_IN 768
#define NLAB 28

// ================= bit-location maps per epoch =================
// state index i (12 bits): i = Σ r_k<<rb[k] | Σ lane_j<<lb[j] | Σ wv_m<<wb[m]
struct Map { int rb[2]; int lb[6]; int wb[4]; };
constexpr Map MP[4] = {
    {{10, 11}, {4, 5, 6, 7, 8, 9}, {0, 1, 2, 3}},
    {{0, 1}, {2, 3, 8, 9, 10, 11}, {4, 5, 6, 7}},
    {{6, 7}, {5, 4, 2, 3, 0, 1}, {8, 9, 10, 11}},   // lb permuted: hot bits 5,4 on DPP lanes
    {{0, 1}, {2, 3, 8, 9, 10, 11}, {4, 5, 6, 7}},
};
constexpr int regPos(int e, int b) { for (int k = 0; k < 2; ++k) if (MP[e].rb[k] == b) return k; return -1; }
constexpr int lanePos(int e, int b) { for (int j = 0; j < 6; ++j) if (MP[e].lb[j] == b) return j; return -1; }
constexpr int wavePos(int e, int b) { for (int m = 0; m < 4; ++m) if (MP[e].wb[m] == b) return m; return -1; }

constexpr int stateOf(int e, int wv, int lane, int r) {
    int i = 0;
    for (int k = 0; k < 2; ++k) i |= ((r >> k) & 1) << MP[e].rb[k];
    for (int j = 0; j < 6; ++j) i |= ((lane >> j) & 1) << MP[e].lb[j];
    for (int m = 0; m < 4; ++m) i |= ((wv >> m) & 1) << MP[e].wb[m];
    return i;
}
constexpr int slotOf(int e, int i) {
    int r = 0, ln = 0, wv = 0;
    for (int k = 0; k < 2; ++k) r |= ((i >> MP[e].rb[k]) & 1) << k;
    for (int j = 0; j < 6; ++j) ln |= ((i >> MP[e].lb[j]) & 1) << j;
    for (int m = 0; m < 4; ++m) wv |= ((i >> MP[e].wb[m]) & 1) << m;
    return (wv << 8) | (ln << 2) | r;
}
constexpr int swzl(int s) { return s ^ (((s >> 4) ^ (s >> 8)) & 15); }  // GF(2)-linear

// ================= cross-lane exchange at distance 2^J =================
template <int J>
__device__ __forceinline__ float lx(float v) {
    if constexpr (J == 0 || J == 1 || J == 3) {
        // xor1: quad_perm[1,0,3,2]=0xB1; xor2: quad_perm[2,3,0,1]=0x4E; xor8: row_ror:8=0x128
        constexpr int ctrl = (J == 0) ? 0xB1 : (J == 1) ? 0x4E : 0x128;
        return __int_as_float(__builtin_amdgcn_update_dpp(
            0, __float_as_int(v), ctrl, 0xF, 0xF, true));
    } else if constexpr (J == 2 || J == 4) {
        constexpr int off = (J == 2) ? 0x101F : 0x401F;  // ds_swizzle xor4 / xor16
        return __int_as_float(__builtin_amdgcn_ds_swizzle(__float_as_int(v), off));
    } else {
        return __shfl_xor(v, 32, 64);
    }
}
__device__ __forceinline__ float waveRed(float v) {
    v += lx<0>(v); v += lx<1>(v); v += lx<2>(v);
    v += lx<3>(v); v += lx<4>(v); v += lx<5>(v);
    return v;
}

// ======= packed-f32 complex helpers: u stored as rr=(ur,ur), im=(-ui,ui) =======
struct CU2 { float2 rr, im; };
struct G4 { CU2 u00, u01, u10, u11; };  // 64 B per gate

__device__ __forceinline__ float2 cmul(const CU2 u, const float2 a) {
    // t = u * a (complex): t.lo = ur*a.x - ui*a.y ; t.hi = ur*a.y + ui*a.x
    float2 t;
    asm("v_pk_mul_f32 %0, %1, %2 op_sel:[0,1] op_sel_hi:[1,0]"
        : "=v"(t) : "v"(u.im), "v"(a));
    asm("v_pk_fma_f32 %0, %1, %2, %3"
        : "=v"(t) : "v"(u.rr), "v"(a), "v"(t));
    return t;
}
__device__ __forceinline__ float2 cfma(const CU2 u, const float2 a, float2 acc) {
    asm("v_pk_fma_f32 %0, %1, %2, %3 op_sel:[0,1,0] op_sel_hi:[1,0,1]"
        : "=v"(acc) : "v"(u.im), "v"(a), "v"(acc));
    asm("v_pk_fma_f32 %0, %1, %2, %3"
        : "=v"(acc) : "v"(u.rr), "v"(a), "v"(acc));
    return acc;
}

// ================= gates =================
template <int E, int B>
__device__ __forceinline__ void rotg(float2 (&a)[4], int lane, const G4& gg) {
    const G4 g = gg;  // 4x ds_read_b128, broadcast
    constexpr int k = regPos(E, B);
    if constexpr (k >= 0) {
        constexpr int m = 1 << k;
#pragma unroll
        for (int r = 0; r < 4; ++r)
            if (!(r & m)) {
                const float2 a0 = a[r], a1 = a[r | m];
                a[r]     = cfma(g.u01, a1, cmul(g.u00, a0));
                a[r | m] = cfma(g.u10, a0, cmul(g.u11, a1));
            }
    } else {
        constexpr int j = lanePos(E, B);
        static_assert(j >= 0, "rot on wave bit");
        const bool hi = (lane >> j) & 1;
        CU2 co, cp;
        co.rr = hi ? g.u11.rr : g.u00.rr;  co.im = hi ? g.u11.im : g.u00.im;
        cp.rr = hi ? g.u10.rr : g.u01.rr;  cp.im = hi ? g.u10.im : g.u01.im;
#pragma unroll
        for (int r = 0; r < 4; ++r) {
            float2 p;
            p.x = lx<j>(a[r].x);
            p.y = lx<j>(a[r].y);
            a[r] = cfma(cp, p, cmul(co, a[r]));
        }
    }
}

template <int E, int C, int T>
__device__ __forceinline__ void cnot(float2 (&a)[4], int lane, int wv) {
    constexpr int kc = regPos(E, C), jc = lanePos(E, C), mc = wavePos(E, C);
    constexpr int kt = regPos(E, T), jt = lanePos(E, T);
    static_assert(wavePos(E, T) < 0, "cnot target on wave bit");
    if constexpr (kt >= 0) {
        constexpr int mt = 1 << kt;
        if constexpr (kc >= 0) {
            constexpr int mcb = 1 << kc;
#pragma unroll
            for (int r = 0; r < 4; ++r)
                if ((r & mcb) && !(r & mt)) { float2 t = a[r]; a[r] = a[r | mt]; a[r | mt] = t; }
        } else if constexpr (jc >= 0) {
            const bool p = (lane >> jc) & 1;
#pragma unroll
            for (int r = 0; r < 4; ++r)
                if (!(r & mt)) {
                    const float2 lo = a[r], hi = a[r | mt];
                    a[r].x = p ? hi.x : lo.x;       a[r].y = p ? hi.y : lo.y;
                    a[r | mt].x = p ? lo.x : hi.x;  a[r | mt].y = p ? lo.y : hi.y;
                }
        } else {
            if ((wv >> mc) & 1) {
#pragma unroll
                for (int r = 0; r < 4; ++r)
                    if (!(r & mt)) { float2 t = a[r]; a[r] = a[r | mt]; a[r | mt] = t; }
            }
        }
    } else {  // target on lane bit jt
        if constexpr (kc >= 0) {
            constexpr int mcb = 1 << kc;
#pragma unroll
            for (int r = 0; r < 4; ++r)
                if (r & mcb) { a[r].x = lx<jt>(a[r].x); a[r].y = lx<jt>(a[r].y); }
        } else if constexpr (jc >= 0) {
            const bool p = (lane >> jc) & 1;
#pragma unroll
            for (int r = 0; r < 4; ++r) {
                const float px = lx<jt>(a[r].x), py = lx<jt>(a[r].y);
                a[r].x = p ? px : a[r].x;  a[r].y = p ? py : a[r].y;
            }
        } else {
            if ((wv >> mc) & 1) {
#pragma unroll
                for (int r = 0; r < 4; ++r) { a[r].x = lx<jt>(a[r].x); a[r].y = lx<jt>(a[r].y); }
            }
        }
    }
}

// remap: write state with mapping PE (linear slots, swizzled), read with mapping CE
template <int PE, int CE>
__device__ __forceinline__ void remap(float2 (&a)[4], int lane, int wv, float2* st) {
    const int wbase = swzl((wv << 8) | (lane << 2));
#pragma unroll
    for (int r = 0; r < 4; ++r) st[wbase ^ r] = a[r];
    __syncthreads();
    const int rbase = swzl(slotOf(PE, stateOf(CE, wv, lane, 0)));
#pragma unroll
    for (int r = 0; r < 4; ++r) {
        const int d = swzl(slotOf(PE, stateOf(CE, 0, 0, r)));  // compile-time folds
        a[r] = st[rbase ^ d];
    }
    __syncthreads();
}

// ============ measurement masks: ring3 (CNOT(w,w+3)) absorbed, GF(2)-derived ============
constexpr int MASKW[12] = {0x124, 0x092, 0x049, 0x900, 0x480, 0x240,
                           0x920, 0x490, 0x248, 0x924, 0x492, 0x249};
constexpr int rmOf(int w) { int v = 0; for (int k = 0; k < 2; ++k) v |= ((MASKW[w] >> MP[3].rb[k]) & 1) << k; return v; }
constexpr int lmOf(int w) { int v = 0; for (int j = 0; j < 6; ++j) v |= ((MASKW[w] >> MP[3].lb[j]) & 1) << j; return v; }
constexpr int wmOf(int w) { int v = 0; for (int m = 0; m < 4; ++m) v |= ((MASKW[w] >> MP[3].wb[m]) & 1) << m; return v; }
constexpr int RMa[12] = {rmOf(0),rmOf(1),rmOf(2),rmOf(3),rmOf(4),rmOf(5),rmOf(6),rmOf(7),rmOf(8),rmOf(9),rmOf(10),rmOf(11)};
constexpr int LMa[12] = {lmOf(0),lmOf(1),lmOf(2),lmOf(3),lmOf(4),lmOf(5),lmOf(6),lmOf(7),lmOf(8),lmOf(9),lmOf(10),lmOf(11)};
constexpr int WMa[12] = {wmOf(0),wmOf(1),wmOf(2),wmOf(3),wmOf(4),wmOf(5),wmOf(6),wmOf(7),wmOf(8),wmOf(9),wmOf(10),wmOf(11)};

// ================= kernel =================
__global__ __launch_bounds__(1024, 8) void hybrid_r6(
    const float* __restrict__ x, const float* __restrict__ proj_w,
    const float* __restrict__ proj_b, const float* __restrict__ ln_w,
    const float* __restrict__ ln_b, const float* __restrict__ q_w,
    const float* __restrict__ h1_w, const float* __restrict__ h1_b,
    const float* __restrict__ h2_w, const float* __restrict__ h2_b,
    float* __restrict__ out) {
    __shared__ float2 st[4096];   // 32 KB remap buffer
    __shared__ G4 rotU[36];       // packed-pair gate matrices
    __shared__ float hbuf[12];
    __shared__ float red[12 * 16];
    __shared__ float z1[256];
    __shared__ float qz[12];

    const int b = blockIdx.x;
    const int tid = threadIdx.x;   // 0..1023
    const int lane = tid & 63;
    const int wv = tid >> 6;       // 0..15

    // ---- 1. projection h[j] = tanh(x[b].proj_w[j] + proj_b[j]) : wave j handles output j ----
    if (wv < 12) {
        const float* xr = x + (size_t)b * D_IN;
        const float* wr = proj_w + wv * D_IN;
        float s = 0.f;
#pragma unroll
        for (int k = 0; k < 12; ++k) s += xr[lane + k * 64] * wr[lane + k * 64];
        s = waveRed(s);
        if (lane == 0) hbuf[wv] = tanhf(s + proj_b[wv]);
    }
    __syncthreads();

    // ---- 2. Rot matrices (packed pairs); layer-0 fused with LayerNorm+RY ----
    if (tid < 36) {
        const float phi = q_w[3 * tid], th = q_w[3 * tid + 1], om = q_w[3 * tid + 2];
        float sth, cth, sa, ca, sb, cb;
        sincosf(0.5f * th, &sth, &cth);
        sincosf(0.5f * (phi + om), &sa, &ca);
        sincosf(0.5f * (phi - om), &sb, &cb);
        float R0r = cth * ca, R0i = -cth * sa;    // U00
        float R1r = -sth * cb, R1i = -sth * sb;   // U01
        float R2r = sth * cb, R2i = -sth * sb;    // U10
        float R3r = cth * ca, R3i = cth * sa;     // U11
        if (tid < 12) {
            float mu = 0.f;
#pragma unroll
            for (int k = 0; k < 12; ++k) mu += hbuf[k];
            mu *= (1.f / 12.f);
            float var = 0.f;
#pragma unroll
            for (int k = 0; k < 12; ++k) { const float d = hbuf[k] - mu; var += d * d; }
            var *= (1.f / 12.f);
            const float inv = 1.f / sqrtf(var + 1e-5f);
            const float ang = (hbuf[tid] - mu) * inv * ln_w[tid] + ln_b[tid];
            float sy, cy;
            sincosf(0.5f * ang, &sy, &cy);
            const float M0r = R0r * cy + R1r * sy, M0i = R0i * cy + R1i * sy;
            const float M1r = -R0r * sy + R1r * cy, M1i = -R0i * sy + R1i * cy;
            const float M2r = R2r * cy + R3r * sy, M2i = R2i * cy + R3i * sy;
            const float M3r = -R2r * sy + R3r * cy, M3i = -R2i * sy + R3i * cy;
            R0r = M0r; R0i = M0i; R1r = M1r; R1i = M1i;
            R2r = M2r; R2i = M2i; R3r = M3r; R3i = M3i;
        }
        G4 g;
        g.u00.rr = make_float2(R0r, R0r); g.u00.im = make_float2(-R0i, R0i);
        g.u01.rr = make_float2(R1r, R1r); g.u01.im = make_float2(-R1i, R1i);
        g.u10.rr = make_float2(R2r, R2r); g.u10.im = make_float2(-R2i, R2i);
        g.u11.rr = make_float2(R3r, R3r); g.u11.im = make_float2(-R3i, R3i);
        rotU[tid] = g;
    }
    __syncthreads();

    // ---- 3. state |0..0>: E0 maps i=0 -> wv0,lane0,r0 ----
    float2 a[4];
#pragma unroll
    for (int r = 0; r < 4; ++r) a[r] = make_float2(0.f, 0.f);
    if (tid == 0) a[0].x = 1.f;

    // ---- 4. circuit ----
    // E0: reg={10,11} lane={4..9} wave={0,1,2,3}
    rotg<0, 11>(a, lane, rotU[0]); rotg<0, 10>(a, lane, rotU[1]); rotg<0, 9>(a, lane, rotU[2]);
    rotg<0, 8>(a, lane, rotU[3]);  rotg<0, 7>(a, lane, rotU[4]);  rotg<0, 6>(a, lane, rotU[5]);
    rotg<0, 5>(a, lane, rotU[6]);  rotg<0, 4>(a, lane, rotU[7]);
    cnot<0, 11, 10>(a, lane, wv); cnot<0, 10, 9>(a, lane, wv); cnot<0, 9, 8>(a, lane, wv);
    cnot<0, 8, 7>(a, lane, wv);   cnot<0, 7, 6>(a, lane, wv);  cnot<0, 6, 5>(a, lane, wv);
    cnot<0, 5, 4>(a, lane, wv);
    remap<0, 1>(a, lane, wv, st);
    // E1: reg={0,1} lane={2,3,8,9,10,11} wave={4,5,6,7}
    rotg<1, 3>(a, lane, rotU[8]); rotg<1, 2>(a, lane, rotU[9]);
    rotg<1, 1>(a, lane, rotU[10]); rotg<1, 0>(a, lane, rotU[11]);
    cnot<1, 4, 3>(a, lane, wv); cnot<1, 3, 2>(a, lane, wv); cnot<1, 2, 1>(a, lane, wv);
    cnot<1, 1, 0>(a, lane, wv); cnot<1, 0, 11>(a, lane, wv);
    rotg<1, 11>(a, lane, rotU[12]); rotg<1, 10>(a, lane, rotU[13]);
    rotg<1, 9>(a, lane, rotU[14]);  rotg<1, 8>(a, lane, rotU[15]);
    rotg<1, 3>(a, lane, rotU[20]);  rotg<1, 2>(a, lane, rotU[21]);
    rotg<1, 1>(a, lane, rotU[22]);  rotg<1, 0>(a, lane, rotU[23]);
    cnot<1, 11, 9>(a, lane, wv); cnot<1, 10, 8>(a, lane, wv);
    remap<1, 2>(a, lane, wv, st);
    // E2: reg={6,7} lane={5,4,2,3,0,1} wave={8,9,10,11}
    rotg<2, 7>(a, lane, rotU[16]); rotg<2, 6>(a, lane, rotU[17]);
    rotg<2, 5>(a, lane, rotU[18]); rotg<2, 4>(a, lane, rotU[19]);
    cnot<2, 9, 7>(a, lane, wv); cnot<2, 8, 6>(a, lane, wv); cnot<2, 7, 5>(a, lane, wv);
    cnot<2, 6, 4>(a, lane, wv); cnot<2, 5, 3>(a, lane, wv); cnot<2, 4, 2>(a, lane, wv);
    cnot<2, 3, 1>(a, lane, wv); cnot<2, 2, 0>(a, lane, wv);
    rotg<2, 7>(a, lane, rotU[28]); rotg<2, 6>(a, lane, rotU[29]);
    rotg<2, 5>(a, lane, rotU[30]); rotg<2, 4>(a, lane, rotU[31]);
    rotg<2, 3>(a, lane, rotU[32]); rotg<2, 2>(a, lane, rotU[33]);
    remap<2, 3>(a, lane, wv, st);
    // E3: reg={0,1} lane={2,3,8,9,10,11} wave={4,5,6,7}
    cnot<3, 1, 11>(a, lane, wv); cnot<3, 0, 10>(a, lane, wv);
    rotg<3, 11>(a, lane, rotU[24]); rotg<3, 10>(a, lane, rotU[25]);
    rotg<3, 9>(a, lane, rotU[26]);  rotg<3, 8>(a, lane, rotU[27]);
    rotg<3, 1>(a, lane, rotU[34]);  rotg<3, 0>(a, lane, rotU[35]);
    // ring3 absorbed into measurement masks.

    // ---- 5. measurement ----
    {
        const float p0 = a[0].x * a[0].x + a[0].y * a[0].y;
        const float p1 = a[1].x * a[1].x + a[1].y * a[1].y;
        const float p2 = a[2].x * a[2].x + a[2].y * a[2].y;
        const float p3 = a[3].x * a[3].x + a[3].y * a[3].y;
        const float s[4] = {p0 + p1 + p2 + p3, p0 - p1 + p2 - p3,
                            p0 + p1 - p2 - p3, p0 - p1 - p2 + p3};
#pragma unroll
        for (int w = 0; w < 12; ++w) {
            const int sgn = (__popc(lane & LMa[w]) + __popc(wv & WMa[w])) & 1;
            float v = sgn ? -s[RMa[w]] : s[RMa[w]];
            v = waveRed(v);
            if (lane == 0) red[w * 16 + wv] = v;
        }
    }
    __syncthreads();
    if (tid < 12) {
        float q = 0.f;
#pragma unroll
        for (int m = 0; m < 16; ++m) q += red[tid * 16 + m];
        qz[tid] = q;
    }
    __syncthreads();

    // ---- 6. MLP hidden: relu(q @ h1_w.T + h1_b) ----
    if (tid < 256) {
        float s = h1_b[tid];
#pragma unroll
        for (int k = 0; k < 12; ++k) s += qz[k] * h1_w[tid * 12 + k];
        z1[tid] = fmaxf(s, 0.f);
    }
    __syncthreads();

    // ---- 7. out = z1 @ h2_w.T + h2_b : waves 0..13, 2 outputs each ----
    if (wv < 14) {
#pragma unroll
        for (int jj = 0; jj < 2; ++jj) {
            const int j = wv * 2 + jj;
            const float* wr = h2_w + j * 256;
            float s = 0.f;
#pragma unroll
            for (int k = 0; k < 4; ++k) s += z1[lane + k * 64] * wr[lane + k * 64];
            s = waveRed(s);
            if (lane == 0) out[(size_t)b * NLAB + j] = s + h2_b[j];
        }
    }
}

extern "C" void kernel_launch(void* const* d_in, const int* in_sizes, int n_in,
                              void* d_out, int out_size, void* d_ws, size_t ws_size,
                              hipStream_t stream) {
    const float* x      = (const float*)d_in[0];
    const float* proj_w = (const float*)d_in[1];
    const float* proj_b = (const float*)d_in[2];
    const float* ln_w   = (const float*)d_in[3];
    const float* ln_b   = (const float*)d_in[4];
    const float* q_w    = (const float*)d_in[5];
    const float* h1_w   = (const float*)d_in[6];
    const float* h1_b   = (const float*)d_in[7];
    const float* h2_w   = (const float*)d_in[8];
    const float* h2_b   = (const float*)d_in[9];
    float* out = (float*)d_out;

    const int B = in_sizes[0] / D_IN;  // 512
    hybrid_r6<<<dim3(B), dim3(1024), 0, stream>>>(x, proj_w, proj_b, ln_w, ln_b,
                                                  q_w, h1_w, h1_b, h2_w, h2_b, out);
}